// Round 1
// baseline (162.948 us; speedup 1.0000x reference)
//
#include <hip/hip_runtime.h>
#include <hip/hip_bf16.h>
#include <math.h>

// LowRankChristoffel: out = clip((((v@U)^2) @ W^T) * (1+sigmoid(x@Vw^T)), +-5)
// B=4, S=4096, D=2048, R=16. All fp32. Memory-bound: 384 MiB min traffic.
//
// Strategy: 256 blocks x 1024 threads; each block owns 64 rows.
// Stage U (then W) TRANSPOSED [r][d] in 128 KiB LDS once per block so the
// per-row full-U reduction streams from LDS (69 TB/s) instead of L2
// (which would be ~4 GiB of L2 traffic and the real bottleneck).

constexpr int D_DIM   = 2048;
constexpr int R_DIM   = 16;
constexpr int ROWS    = 64;     // rows per block
constexpr int THREADS = 1024;   // 16 waves

// dynamic LDS layout (floats):
//   w_lds  [R_DIM][D_DIM]  = 32768  (U, later overwritten with W)
//   vw_lds [D_DIM]         =  2048
//   sq_lds [ROWS][R_DIM]   =  1024
//   fac_lds[ROWS]          =    64
constexpr int SMEM_FLOATS = R_DIM * D_DIM + D_DIM + ROWS * R_DIM + ROWS;
constexpr size_t SMEM_BYTES = (size_t)SMEM_FLOATS * sizeof(float);

__device__ __forceinline__ float clamp5(float v) {
    return fminf(fmaxf(v, -5.0f), 5.0f);
}

extern "C" __global__ void __launch_bounds__(THREADS)
lrc_kernel(const float* __restrict__ v, const float* __restrict__ x,
           const float* __restrict__ U, const float* __restrict__ W,
           const float* __restrict__ Vw, float* __restrict__ out, int nrows)
{
    extern __shared__ float smem[];
    float* w_lds   = smem;                         // [R_DIM][D_DIM]
    float* vw_lds  = w_lds + R_DIM * D_DIM;        // [D_DIM]
    float* sq_lds  = vw_lds + D_DIM;               // [ROWS][R_DIM]
    float* fac_lds = sq_lds + ROWS * R_DIM;        // [ROWS]

    const int tid  = threadIdx.x;
    const int lane = tid & 63;
    const int wave = tid >> 6;           // 0..15
    const int row0 = blockIdx.x * ROWS;

    // ---- stage Vw into LDS (coalesced float4) ----
    for (int i = tid; i < D_DIM / 4; i += THREADS) {
        reinterpret_cast<float4*>(vw_lds)[i] =
            reinterpret_cast<const float4*>(Vw)[i];
    }

    // ---- stage U transposed: thread handles d rows 2*tid, 2*tid+1 ----
    {
        const int dd = tid * 2;
        float u0[R_DIM], u1[R_DIM];
        const float4* p0 = reinterpret_cast<const float4*>(U + (size_t)dd * R_DIM);
        const float4* p1 = reinterpret_cast<const float4*>(U + (size_t)(dd + 1) * R_DIM);
        #pragma unroll
        for (int c = 0; c < 4; ++c) {
            *reinterpret_cast<float4*>(&u0[c * 4]) = p0[c];
            *reinterpret_cast<float4*>(&u1[c * 4]) = p1[c];
        }
        #pragma unroll
        for (int r = 0; r < R_DIM; ++r) {
            *reinterpret_cast<float2*>(&w_lds[r * D_DIM + dd]) = make_float2(u0[r], u1[r]);
        }
    }
    __syncthreads();

    // ---- phase 1: proj^2 and modulation factor per row ----
    #pragma unroll
    for (int j = 0; j < ROWS / 16; ++j) {
        const int rl = j * 16 + wave;          // local row 0..63
        const int row = row0 + rl;
        if (row < nrows) {
            const float* vrow = v + (size_t)row * D_DIM;
            const float* xrow = x + (size_t)row * D_DIM;
            float pp[R_DIM];
            #pragma unroll
            for (int r = 0; r < R_DIM; ++r) pp[r] = 0.0f;
            float xv = 0.0f;
            #pragma unroll
            for (int i = 0; i < D_DIM / 256; ++i) {      // 8 iters
                const int d0 = i * 256 + lane * 4;
                const float4 v4  = *reinterpret_cast<const float4*>(vrow + d0);
                const float4 x4  = *reinterpret_cast<const float4*>(xrow + d0);
                const float4 vw4 = *reinterpret_cast<const float4*>(vw_lds + d0);
                xv += x4.x * vw4.x + x4.y * vw4.y + x4.z * vw4.z + x4.w * vw4.w;
                #pragma unroll
                for (int r = 0; r < R_DIM; ++r) {
                    const float4 u4 = *reinterpret_cast<const float4*>(w_lds + r * D_DIM + d0);
                    pp[r] += v4.x * u4.x + v4.y * u4.y + v4.z * u4.z + v4.w * u4.w;
                }
            }
            // butterfly reduce across the 64-lane wave
            #pragma unroll
            for (int s = 32; s >= 1; s >>= 1) {
                xv += __shfl_xor(xv, s, 64);
                #pragma unroll
                for (int r = 0; r < R_DIM; ++r) pp[r] += __shfl_xor(pp[r], s, 64);
            }
            if (lane == 0) {
                #pragma unroll
                for (int r = 0; r < R_DIM; ++r) sq_lds[rl * R_DIM + r] = pp[r] * pp[r];
                fac_lds[rl] = 1.0f + 1.0f / (1.0f + __expf(-xv));
            }
        }
    }
    __syncthreads();   // everyone done reading U

    // ---- restage W transposed over U's LDS ----
    {
        const int dd = tid * 2;
        float u0[R_DIM], u1[R_DIM];
        const float4* p0 = reinterpret_cast<const float4*>(W + (size_t)dd * R_DIM);
        const float4* p1 = reinterpret_cast<const float4*>(W + (size_t)(dd + 1) * R_DIM);
        #pragma unroll
        for (int c = 0; c < 4; ++c) {
            *reinterpret_cast<float4*>(&u0[c * 4]) = p0[c];
            *reinterpret_cast<float4*>(&u1[c * 4]) = p1[c];
        }
        #pragma unroll
        for (int r = 0; r < R_DIM; ++r) {
            *reinterpret_cast<float2*>(&w_lds[r * D_DIM + dd]) = make_float2(u0[r], u1[r]);
        }
    }
    __syncthreads();

    // ---- phase 2: out[row][d] = clamp(fac * sum_r sq[r]*W[d][r]) ----
    #pragma unroll
    for (int j = 0; j < ROWS / 16; ++j) {
        const int rl = j * 16 + wave;
        const int row = row0 + rl;
        if (row < nrows) {
            float* orow = out + (size_t)row * D_DIM;
            float sq[R_DIM];
            #pragma unroll
            for (int r = 0; r < R_DIM; ++r) sq[r] = sq_lds[rl * R_DIM + r];
            const float fac = fac_lds[rl];
            #pragma unroll
            for (int i = 0; i < D_DIM / 256; ++i) {
                const int d0 = i * 256 + lane * 4;
                float4 o = make_float4(0.f, 0.f, 0.f, 0.f);
                #pragma unroll
                for (int r = 0; r < R_DIM; ++r) {
                    const float4 w4 = *reinterpret_cast<const float4*>(w_lds + r * D_DIM + d0);
                    o.x += sq[r] * w4.x;
                    o.y += sq[r] * w4.y;
                    o.z += sq[r] * w4.z;
                    o.w += sq[r] * w4.w;
                }
                o.x = clamp5(o.x * fac);
                o.y = clamp5(o.y * fac);
                o.z = clamp5(o.z * fac);
                o.w = clamp5(o.w * fac);
                *reinterpret_cast<float4*>(orow + d0) = o;
            }
        }
    }
}

extern "C" void kernel_launch(void* const* d_in, const int* in_sizes, int n_in,
                              void* d_out, int out_size, void* d_ws, size_t ws_size,
                              hipStream_t stream) {
    const float* v  = (const float*)d_in[0];
    const float* x  = (const float*)d_in[1];
    const float* U  = (const float*)d_in[2];
    const float* W  = (const float*)d_in[3];
    const float* Vw = (const float*)d_in[4];
    float* out = (float*)d_out;

    const int nrows = in_sizes[0] / D_DIM;            // B*S = 16384
    const int grid  = (nrows + ROWS - 1) / ROWS;      // 256

    hipFuncSetAttribute((const void*)lrc_kernel,
                        hipFuncAttributeMaxDynamicSharedMemorySize,
                        (int)SMEM_BYTES);
    lrc_kernel<<<grid, THREADS, SMEM_BYTES, stream>>>(v, x, U, W, Vw, out, nrows);
}